// Round 5
// baseline (1116.194 us; speedup 1.0000x reference)
//
#include <hip/hip_runtime.h>

#define DIM 64
#define D2  128

// Workspace budget: ~255 MB (ea_s 204.8M + sed 6.4M + h 12.8M + h1 25.6M + aux).

// ---------------- edge_index dtype autodetect ----------------
__global__ void k_detect(const int* __restrict__ ei, int m, int* __restrict__ flag) {
  __shared__ int nz;
  int t = threadIdx.x;
  if (t == 0) nz = 0;
  __syncthreads();
  int lim = 4096;
  if (lim > m / 2) lim = m / 2;
  int any = 0;
  for (int i = t; i < lim; i += 256) any |= (ei[2 * i + 1] != 0);
  if (any) atomicOr(&nz, 1);
  __syncthreads();
  if (t == 0) flag[0] = nz ? 0 : 1;  // 1 => int64 storage
}

// ---------------- counting sort by dst ----------------
__global__ void k_hist(const int* __restrict__ ei, int m, const int* __restrict__ flag,
                       int* __restrict__ cnt) {
  int i = blockIdx.x * 256 + threadIdx.x;
  if (i >= m) return;
  int f = flag[0];
  int d = f ? ei[2 * ((size_t)m + i)] : ei[(size_t)m + i];
  atomicAdd(&cnt[d], 1);
}

__global__ void k_scanA(const int* __restrict__ cnt, int* __restrict__ excl,
                        int* __restrict__ bsum, int n) {
  __shared__ int lds[256];
  int t = threadIdx.x;
  int i = blockIdx.x * 256 + t;
  int v = (i < n) ? cnt[i] : 0;
  lds[t] = v;
  __syncthreads();
  for (int off = 1; off < 256; off <<= 1) {
    int u = (t >= off) ? lds[t - off] : 0;
    __syncthreads();
    lds[t] += u;
    __syncthreads();
  }
  if (i < n) excl[i] = lds[t] - v;
  if (t == 255) bsum[blockIdx.x] = lds[255];
}

__global__ void k_scanB(const int* __restrict__ bsum, int* __restrict__ boff, int nb) {
  __shared__ int lds[256];
  int t = threadIdx.x;
  int v = (t < nb) ? bsum[t] : 0;
  lds[t] = v;
  __syncthreads();
  for (int off = 1; off < 256; off <<= 1) {
    int u = (t >= off) ? lds[t - off] : 0;
    __syncthreads();
    lds[t] += u;
    __syncthreads();
  }
  if (t < nb) boff[t] = lds[t] - v;
}

__global__ void k_scanC(const int* __restrict__ excl, const int* __restrict__ boff,
                        int* __restrict__ start, int* __restrict__ cursor, int n, int m) {
  int i = blockIdx.x * 256 + threadIdx.x;
  if (i < n) {
    int s = excl[i] + boff[i >> 8];
    start[i] = s;
    cursor[i] = s;
  }
  if (i == 0) start[n] = m;
}

__global__ void k_scatter(const int* __restrict__ ei, int m, const int* __restrict__ flag,
                          int* __restrict__ cursor, int2* __restrict__ sed) {
  int i = blockIdx.x * 256 + threadIdx.x;
  if (i >= m) return;
  int f = flag[0];
  int s, d;
  if (f) { s = ei[2 * (size_t)i]; d = ei[2 * ((size_t)m + i)]; }
  else   { s = ei[i];             d = ei[(size_t)m + i]; }
  int pos = atomicAdd(&cursor[d], 1);
  sed[pos] = make_int2(i, s);
}

// Deterministic order: insertion-sort each node's segment by edge id so the
// aggregation order (and hence fp rounding) is bitwise identical every call.
__global__ void k_sortseg(int2* __restrict__ sed, const int* __restrict__ start, int n) {
  int v = blockIdx.x * 256 + threadIdx.x;
  if (v >= n) return;
  int s0 = start[v], s1 = start[v + 1];
  for (int p = s0 + 1; p < s1; p++) {
    int2 key = sed[p];
    int q = p - 1;
    while (q >= s0) {
      int2 t = sed[q];
      if (t.x <= key.x) break;
      sed[q + 1] = t;
      q--;
    }
    sed[q + 1] = key;
  }
}

// ---------------- permute edge_attr into dst-sorted order (paid once) ----------
// After this, every k_agg pass reads ea_s sequentially (streaming) instead of
// doing an 800k-row random gather per layer. Also emits srcs[p] so k_agg no
// longer needs edge ids at all.
__global__ __launch_bounds__(256) void k_gather(
    const float* __restrict__ ea, const int2* __restrict__ sed,
    float* __restrict__ ea_s, int* __restrict__ srcs, int m) {
  int t = threadIdx.x;
  int e = blockIdx.x * 16 + (t >> 4);
  int l = t & 15;
  if (e >= m) return;
  int2 es = sed[e];  // 16 lanes same address -> broadcast
  float4 v = *(const float4*)&ea[(size_t)es.x * DIM + l * 4];
  *(float4*)&ea_s[(size_t)e * DIM + l * 4] = v;
  if (l == 0) srcs[e] = es.y;
}

// ---------------- per-node online-softmax aggregation + residual ----------------
// One wave per node. Lane = (sub, cl): sub = lane>>4 picks one of 4 edges in
// flight; cl = lane&15 picks 4 channels (float4). ea_s reads are sequential;
// only x[src] is a gather (12.8 MB working set, L2/L3-resident). States merged
// across sub via shfl_xor (fixed structure -> bitwise deterministic).
__global__ __launch_bounds__(256) void k_agg(
    const float* __restrict__ x, const float* __restrict__ ea_s,
    const int* __restrict__ srcs, const int* __restrict__ start,
    float* __restrict__ h, int n) {
  int lane = threadIdx.x & 63;
  int node = blockIdx.x * 4 + (threadIdx.x >> 6);
  if (node >= n) return;
  int sub = lane >> 4;
  int cl = lane & 15;
  int s0 = start[node], s1 = start[node + 1];

  float m0 = 0.f, m1 = 0.f, m2 = 0.f, m3 = 0.f;  // msg > 0 always: 0 is neutral
  float ss0 = 0.f, ss1 = 0.f, ss2 = 0.f, ss3 = 0.f;
  float w0 = 0.f, w1 = 0.f, w2 = 0.f, w3 = 0.f;

  for (int base = s0; base < s1; base += 64) {
    int cnt = s1 - base;
    if (cnt > 64) cnt = 64;
    int sdata = 0;
    if (lane < cnt) sdata = srcs[base + lane];  // coalesced pre-stage
    int nIter = (cnt + 3) >> 2;
    for (int t = 0; t < nIter; t++) {
      int idx = 4 * t + sub;
      int src = __shfl(sdata, idx, 64);
      if (idx < cnt) {
        float4 xv = *(const float4*)&x[(size_t)src * DIM + cl * 4];
        float4 av = *(const float4*)&ea_s[(size_t)(base + idx) * DIM + cl * 4];
        float g;
        g = fmaxf(xv.x + av.x, 0.f) + 1e-7f;
        { float nm = fmaxf(m0, g); float sc = __expf(m0 - nm); float pv = __expf(g - nm);
          ss0 = ss0 * sc + pv; w0 = w0 * sc + g * pv; m0 = nm; }
        g = fmaxf(xv.y + av.y, 0.f) + 1e-7f;
        { float nm = fmaxf(m1, g); float sc = __expf(m1 - nm); float pv = __expf(g - nm);
          ss1 = ss1 * sc + pv; w1 = w1 * sc + g * pv; m1 = nm; }
        g = fmaxf(xv.z + av.z, 0.f) + 1e-7f;
        { float nm = fmaxf(m2, g); float sc = __expf(m2 - nm); float pv = __expf(g - nm);
          ss2 = ss2 * sc + pv; w2 = w2 * sc + g * pv; m2 = nm; }
        g = fmaxf(xv.w + av.w, 0.f) + 1e-7f;
        { float nm = fmaxf(m3, g); float sc = __expf(m3 - nm); float pv = __expf(g - nm);
          ss3 = ss3 * sc + pv; w3 = w3 * sc + g * pv; m3 = nm; }
      }
    }
  }

  // merge the 4 per-sub partial states (lanes differing only in bits 4..5)
#pragma unroll
  for (int off = 16; off < 64; off <<= 1) {
    float om, os, ow, M, e1, e2;
    om = __shfl_xor(m0, off, 64); os = __shfl_xor(ss0, off, 64); ow = __shfl_xor(w0, off, 64);
    M = fmaxf(m0, om); e1 = __expf(m0 - M); e2 = __expf(om - M);
    ss0 = ss0 * e1 + os * e2; w0 = w0 * e1 + ow * e2; m0 = M;
    om = __shfl_xor(m1, off, 64); os = __shfl_xor(ss1, off, 64); ow = __shfl_xor(w1, off, 64);
    M = fmaxf(m1, om); e1 = __expf(m1 - M); e2 = __expf(om - M);
    ss1 = ss1 * e1 + os * e2; w1 = w1 * e1 + ow * e2; m1 = M;
    om = __shfl_xor(m2, off, 64); os = __shfl_xor(ss2, off, 64); ow = __shfl_xor(w2, off, 64);
    M = fmaxf(m2, om); e1 = __expf(m2 - M); e2 = __expf(om - M);
    ss2 = ss2 * e1 + os * e2; w2 = w2 * e1 + ow * e2; m2 = M;
    om = __shfl_xor(m3, off, 64); os = __shfl_xor(ss3, off, 64); ow = __shfl_xor(w3, off, 64);
    M = fmaxf(m3, om); e1 = __expf(m3 - M); e2 = __expf(om - M);
    ss3 = ss3 * e1 + os * e2; w3 = w3 * e1 + ow * e2; m3 = M;
  }

  if (sub == 0) {
    float4 xr = *(const float4*)&x[(size_t)node * DIM + cl * 4];
    float4 o;
    o.x = w0 / fmaxf(ss0, 1e-16f) + xr.x;
    o.y = w1 / fmaxf(ss1, 1e-16f) + xr.y;
    o.z = w2 / fmaxf(ss2, 1e-16f) + xr.z;
    o.w = w3 / fmaxf(ss3, 1e-16f) + xr.w;
    *(float4*)&h[(size_t)node * DIM + cl * 4] = o;
  }
}

// ---------------- GEMM1: h[N,64] @ W1[64,128] + b1, fused BN partial stats ----------------
__global__ __launch_bounds__(256) void k_gemm1(
    const float* __restrict__ h, const float* __restrict__ W1,
    const float* __restrict__ b1, float* __restrict__ h1,
    float* __restrict__ ps, float* __restrict__ pq, int n) {
  __shared__ float ws[DIM * D2];   // 32 KB
  __shared__ float hs[DIM][68];    // [d][row], padded
  __shared__ float red[8][D2];     // deterministic BN partial reduction
  int tid = threadIdx.x;
  int row0 = blockIdx.x * 64;
  const float4* w4 = (const float4*)W1;
  float4* ws4 = (float4*)ws;
#pragma unroll
  for (int i = 0; i < 8; i++) ws4[tid + 256 * i] = w4[tid + 256 * i];
  const float4* h4 = (const float4*)h;
#pragma unroll
  for (int i = 0; i < 4; i++) {
    int idx = tid + 256 * i;
    int r = idx & 63, dg = idx >> 6;
    int row = row0 + r;
    float4 v = make_float4(0.f, 0.f, 0.f, 0.f);
    if (row < n) v = h4[(size_t)row * 16 + dg];
    int c = dg * 4;
    hs[c + 0][r] = v.x; hs[c + 1][r] = v.y; hs[c + 2][r] = v.z; hs[c + 3][r] = v.w;
  }
  __syncthreads();

  int tc = tid & 31, tr = tid >> 5;  // 4 cols x 8 rows per thread
  float bb[4];
#pragma unroll
  for (int k = 0; k < 4; k++) bb[k] = b1[tc * 4 + k];
  float acc[8][4];
#pragma unroll
  for (int i = 0; i < 8; i++)
#pragma unroll
    for (int k = 0; k < 4; k++) acc[i][k] = bb[k];
  // partial unroll only: full unroll spilled to scratch (R1: 452 MB fetch/dispatch)
#pragma unroll 4
  for (int d = 0; d < DIM; d++) {
    float4 wv = *(const float4*)&ws[d * D2 + tc * 4];
    float4 ha = *(const float4*)&hs[d][tr * 8];
    float4 hb = *(const float4*)&hs[d][tr * 8 + 4];
    float hr[8] = {ha.x, ha.y, ha.z, ha.w, hb.x, hb.y, hb.z, hb.w};
    float wk[4] = {wv.x, wv.y, wv.z, wv.w};
#pragma unroll
    for (int i = 0; i < 8; i++)
#pragma unroll
      for (int k = 0; k < 4; k++) acc[i][k] = fmaf(hr[i], wk[k], acc[i][k]);
  }
  float cs[4] = {0.f, 0.f, 0.f, 0.f}, cq[4] = {0.f, 0.f, 0.f, 0.f};
#pragma unroll
  for (int i = 0; i < 8; i++) {
    int row = row0 + tr * 8 + i;
    if (row < n) {
      ((float4*)h1)[(size_t)row * 32 + tc] =
          make_float4(acc[i][0], acc[i][1], acc[i][2], acc[i][3]);
#pragma unroll
      for (int k = 0; k < 4; k++) { cs[k] += acc[i][k]; cq[k] += acc[i][k] * acc[i][k]; }
    }
  }
  // deterministic (fixed-order) reduction of BN partials — no float atomics
  __syncthreads();
#pragma unroll
  for (int k = 0; k < 4; k++) red[tr][tc * 4 + k] = cs[k];
  __syncthreads();
  float asum = 0.f;
  if (tid < D2) {
#pragma unroll
    for (int r = 0; r < 8; r++) asum += red[r][tid];
  }
  __syncthreads();
#pragma unroll
  for (int k = 0; k < 4; k++) red[tr][tc * 4 + k] = cq[k];
  __syncthreads();
  if (tid < D2) {
    float bsumv = 0.f;
#pragma unroll
    for (int r = 0; r < 8; r++) bsumv += red[r][tid];
    ps[(size_t)blockIdx.x * D2 + tid] = asum;
    pq[(size_t)blockIdx.x * D2 + tid] = bsumv;
  }
}

// ---------------- finalize BN: fold gamma/beta into scale/shift ----------------
__global__ void k_stats(const float* __restrict__ ps, const float* __restrict__ pq,
                        const float* __restrict__ gamma, const float* __restrict__ beta,
                        float* __restrict__ ss, int rows, int n) {
  __shared__ float t0[D2], t1[D2];
  int t = threadIdx.x;
  int j = t & (D2 - 1);
  int half = t >> 7;
  float a = 0.f, b = 0.f;
  for (int r = half; r < rows; r += 2) {
    a += ps[(size_t)r * D2 + j];
    b += pq[(size_t)r * D2 + j];
  }
  if (half) { t0[j] = a; t1[j] = b; }
  __syncthreads();
  if (!half) {
    a += t0[j]; b += t1[j];
    float mu = a / (float)n;
    float var = b / (float)n - mu * mu;
    float sc = gamma[j] * rsqrtf(var + 1e-5f);
    ss[j] = sc;
    ss[D2 + j] = beta[j] - mu * sc;
  }
}

// ---------------- GEMM2: relu(BN(h1))[N,128] @ W2[128,64] + b2 ----------------
__global__ __launch_bounds__(256) void k_gemm2(
    const float* __restrict__ h1, const float* __restrict__ W2,
    const float* __restrict__ b2, const float* __restrict__ ss,
    float* __restrict__ out, int n) {
  __shared__ float ws2[D2 * DIM];  // 32 KB
  __shared__ float hs[D2][68];     // 34.8 KB
  __shared__ float scS[D2], shS[D2];
  int tid = threadIdx.x;
  int row0 = blockIdx.x * 64;
  const float4* w4 = (const float4*)W2;
  float4* ws4 = (float4*)ws2;
#pragma unroll
  for (int i = 0; i < 8; i++) ws4[tid + 256 * i] = w4[tid + 256 * i];
  if (tid < D2) { scS[tid] = ss[tid]; shS[tid] = ss[D2 + tid]; }
  __syncthreads();
  const float4* h14 = (const float4*)h1;
#pragma unroll
  for (int i = 0; i < 8; i++) {
    int idx = tid + 256 * i;
    int r = idx & 63, cg = idx >> 6;
    int row = row0 + r;
    float4 v = make_float4(0.f, 0.f, 0.f, 0.f);
    if (row < n) v = h14[(size_t)row * 32 + cg];
    int c = cg * 4;
    hs[c + 0][r] = fmaxf(fmaf(v.x, scS[c + 0], shS[c + 0]), 0.f);
    hs[c + 1][r] = fmaxf(fmaf(v.y, scS[c + 1], shS[c + 1]), 0.f);
    hs[c + 2][r] = fmaxf(fmaf(v.z, scS[c + 2], shS[c + 2]), 0.f);
    hs[c + 3][r] = fmaxf(fmaf(v.w, scS[c + 3], shS[c + 3]), 0.f);
  }
  __syncthreads();
  int tc = tid & 15, tr = tid >> 4;  // 4 cols x 4 rows per thread
  float bb[4];
#pragma unroll
  for (int k = 0; k < 4; k++) bb[k] = b2[tc * 4 + k];
  float acc[4][4];
#pragma unroll
  for (int i = 0; i < 4; i++)
#pragma unroll
    for (int k = 0; k < 4; k++) acc[i][k] = bb[k];
  // partial unroll only: full unroll spilled to scratch (R1: 452 MB fetch/dispatch)
#pragma unroll 4
  for (int d = 0; d < D2; d++) {
    float4 wv = *(const float4*)&ws2[d * DIM + tc * 4];
    float4 hv = *(const float4*)&hs[d][tr * 4];
    float hr[4] = {hv.x, hv.y, hv.z, hv.w};
    float wk[4] = {wv.x, wv.y, wv.z, wv.w};
#pragma unroll
    for (int i = 0; i < 4; i++)
#pragma unroll
      for (int k = 0; k < 4; k++) acc[i][k] = fmaf(hr[i], wk[k], acc[i][k]);
  }
#pragma unroll
  for (int i = 0; i < 4; i++) {
    int row = row0 + tr * 4 + i;
    if (row < n)
      ((float4*)out)[(size_t)row * 16 + tc] =
          make_float4(acc[i][0], acc[i][1], acc[i][2], acc[i][3]);
  }
}

extern "C" void kernel_launch(void* const* d_in, const int* in_sizes, int n_in,
                              void* d_out, int out_size, void* d_ws, size_t ws_size,
                              hipStream_t stream) {
  (void)n_in; (void)out_size; (void)ws_size;
  const float* x0    = (const float*)d_in[0];
  const int*   ei    = (const int*)d_in[1];
  const float* ea    = (const float*)d_in[2];
  const float* W1    = (const float*)d_in[3];
  const float* b1    = (const float*)d_in[4];
  const float* gamma = (const float*)d_in[5];
  const float* beta  = (const float*)d_in[6];
  const float* W2    = (const float*)d_in[7];
  const float* b2    = (const float*)d_in[8];
  float* out = (float*)d_out;

  int n = in_sizes[0] / DIM;   // 50000
  int m = in_sizes[1] / 2;     // 800000

  char* base = (char*)d_ws;
  size_t off = 0;
  auto alloc = [&](size_t bytes) -> void* {
    void* p = base + off;
    off += (bytes + 255) & ~(size_t)255;
    return p;
  };
  int*   cnt    = (int*)alloc((size_t)n * 4);
  int*   excl   = (int*)alloc((size_t)n * 4);
  int*   bsum   = (int*)alloc(256 * 4);
  int*   boff   = (int*)alloc(256 * 4);
  int*   start  = (int*)alloc((size_t)(n + 1) * 4);
  int*   cursor = (int*)alloc((size_t)n * 4);
  int*   flag   = (int*)alloc(256);
  int2*  sed    = (int2*)alloc((size_t)m * 8);
  int*   srcs   = (int*)alloc((size_t)m * 4);
  float* ea_s   = (float*)alloc((size_t)m * DIM * 4);  // 204.8 MB
  float* h      = (float*)alloc((size_t)n * DIM * 4);
  float* h1     = (float*)alloc((size_t)n * D2 * 4);
  int tiles = (n + 63) / 64;
  float* ps = (float*)alloc((size_t)tiles * D2 * 4);
  float* pq = (float*)alloc((size_t)tiles * D2 * 4);
  float* ss = (float*)alloc(256 * 4);

  hipMemsetAsync(cnt, 0, (size_t)n * 4, stream);
  k_detect<<<1, 256, 0, stream>>>(ei, m, flag);
  int mg = (m + 255) / 256;
  int ng = (n + 255) / 256;
  k_hist<<<mg, 256, 0, stream>>>(ei, m, flag, cnt);
  k_scanA<<<ng, 256, 0, stream>>>(cnt, excl, bsum, n);
  k_scanB<<<1, 256, 0, stream>>>(bsum, boff, ng);
  k_scanC<<<ng, 256, 0, stream>>>(excl, boff, start, cursor, n, m);
  k_scatter<<<mg, 256, 0, stream>>>(ei, m, flag, cursor, sed);
  k_sortseg<<<ng, 256, 0, stream>>>(sed, start, n);
  k_gather<<<(m + 15) / 16, 256, 0, stream>>>(ea, sed, ea_s, srcs, m);

  for (int l = 0; l < 3; l++) {
    const float* xin = (l == 0) ? x0 : out;
    k_agg<<<(n + 3) / 4, 256, 0, stream>>>(xin, ea_s, srcs, start, h, n);
    k_gemm1<<<tiles, 256, 0, stream>>>(h, W1 + (size_t)l * DIM * D2, b1 + (size_t)l * D2,
                                       h1, ps, pq, n);
    k_stats<<<1, 256, 0, stream>>>(ps, pq, gamma + (size_t)l * D2, beta + (size_t)l * D2,
                                   ss, tiles, n);
    k_gemm2<<<tiles, 256, 0, stream>>>(h1, W2 + (size_t)l * D2 * DIM, b2 + (size_t)l * DIM,
                                       ss, out, n);
  }
}

// Round 6
// 749.406 us; speedup vs baseline: 1.4894x; 1.4894x over previous
//
#include <hip/hip_runtime.h>

#define DIM 64
#define D2  128

// Workspace budget: ~46.4 MB (sed 6.4M + h 12.8M + h1 25.6M + aux).

// ---------------- edge_index dtype autodetect ----------------
__global__ void k_detect(const int* __restrict__ ei, int m, int* __restrict__ flag) {
  __shared__ int nz;
  int t = threadIdx.x;
  if (t == 0) nz = 0;
  __syncthreads();
  int lim = 4096;
  if (lim > m / 2) lim = m / 2;
  int any = 0;
  for (int i = t; i < lim; i += 256) any |= (ei[2 * i + 1] != 0);
  if (any) atomicOr(&nz, 1);
  __syncthreads();
  if (t == 0) flag[0] = nz ? 0 : 1;  // 1 => int64 storage
}

// ---------------- counting sort by dst ----------------
__global__ void k_hist(const int* __restrict__ ei, int m, const int* __restrict__ flag,
                       int* __restrict__ cnt) {
  int i = blockIdx.x * 256 + threadIdx.x;
  if (i >= m) return;
  int f = flag[0];
  int d = f ? ei[2 * ((size_t)m + i)] : ei[(size_t)m + i];
  atomicAdd(&cnt[d], 1);
}

__global__ void k_scanA(const int* __restrict__ cnt, int* __restrict__ excl,
                        int* __restrict__ bsum, int n) {
  __shared__ int lds[256];
  int t = threadIdx.x;
  int i = blockIdx.x * 256 + t;
  int v = (i < n) ? cnt[i] : 0;
  lds[t] = v;
  __syncthreads();
  for (int off = 1; off < 256; off <<= 1) {
    int u = (t >= off) ? lds[t - off] : 0;
    __syncthreads();
    lds[t] += u;
    __syncthreads();
  }
  if (i < n) excl[i] = lds[t] - v;
  if (t == 255) bsum[blockIdx.x] = lds[255];
}

__global__ void k_scanB(const int* __restrict__ bsum, int* __restrict__ boff, int nb) {
  __shared__ int lds[256];
  int t = threadIdx.x;
  int v = (t < nb) ? bsum[t] : 0;
  lds[t] = v;
  __syncthreads();
  for (int off = 1; off < 256; off <<= 1) {
    int u = (t >= off) ? lds[t - off] : 0;
    __syncthreads();
    lds[t] += u;
    __syncthreads();
  }
  if (t < nb) boff[t] = lds[t] - v;
}

__global__ void k_scanC(const int* __restrict__ excl, const int* __restrict__ boff,
                        int* __restrict__ start, int* __restrict__ cursor, int n, int m) {
  int i = blockIdx.x * 256 + threadIdx.x;
  if (i < n) {
    int s = excl[i] + boff[i >> 8];
    start[i] = s;
    cursor[i] = s;
  }
  if (i == 0) start[n] = m;
}

__global__ void k_scatter(const int* __restrict__ ei, int m, const int* __restrict__ flag,
                          int* __restrict__ cursor, int2* __restrict__ sed) {
  int i = blockIdx.x * 256 + threadIdx.x;
  if (i >= m) return;
  int f = flag[0];
  int s, d;
  if (f) { s = ei[2 * (size_t)i]; d = ei[2 * ((size_t)m + i)]; }
  else   { s = ei[i];             d = ei[(size_t)m + i]; }
  int pos = atomicAdd(&cursor[d], 1);
  sed[pos] = make_int2(i, s);
}

// Deterministic order: insertion-sort each node's segment by edge id so the
// aggregation order (and hence fp rounding) is bitwise identical every call.
__global__ void k_sortseg(int2* __restrict__ sed, const int* __restrict__ start, int n) {
  int v = blockIdx.x * 256 + threadIdx.x;
  if (v >= n) return;
  int s0 = start[v], s1 = start[v + 1];
  for (int p = s0 + 1; p < s1; p++) {
    int2 key = sed[p];
    int q = p - 1;
    while (q >= s0) {
      int2 t = sed[q];
      if (t.x <= key.x) break;
      sed[q + 1] = t;
      q--;
    }
    sed[q + 1] = key;
  }
}

// ---------------- per-node online-softmax aggregation + residual ----------------
// One wave per node. Lane = (sub, cl): sub = lane>>3 picks one of 8 edges in
// flight; cl = lane&7 picks 8 channels (2x float4). Each lane keeps 8 online
// softmax states; states merged across sub via shfl_xor (fixed structure ->
// bitwise deterministic). ea read stays a direct 256B-row gather: R5 showed
// materializing a sorted copy costs more than it saves.
__global__ __launch_bounds__(256) void k_agg(
    const float* __restrict__ x, const float* __restrict__ ea,
    const int2* __restrict__ sed, const int* __restrict__ start,
    float* __restrict__ h, int n) {
  int lane = threadIdx.x & 63;
  int node = blockIdx.x * 4 + (threadIdx.x >> 6);
  if (node >= n) return;
  int sub = lane >> 3;  // 0..7: edge slot
  int cl = lane & 7;    // 0..7: channel group (8 floats)
  int s0 = start[node], s1 = start[node + 1];

  float mM[8], sS[8], wW[8];
#pragma unroll
  for (int c = 0; c < 8; c++) { mM[c] = 0.f; sS[c] = 0.f; wW[c] = 0.f; }

  for (int base = s0; base < s1; base += 64) {
    int cnt = s1 - base;
    if (cnt > 64) cnt = 64;
    long long edata = 0;
    if (lane < cnt) edata = *(const long long*)&sed[base + lane];
    int nIter = (cnt + 7) >> 3;
    for (int t = 0; t < nIter; t++) {
      int idx = 8 * t + sub;
      long long ed = __shfl(edata, idx, 64);
      if (idx < cnt) {
        int eid = (int)(ed & 0xffffffffLL);
        int src = (int)((unsigned long long)ed >> 32);
        const float* xr = &x[(size_t)src * DIM + cl * 8];
        const float* ar = &ea[(size_t)eid * DIM + cl * 8];
        float4 xa = *(const float4*)xr;
        float4 xb = *(const float4*)(xr + 4);
        float4 aa = *(const float4*)ar;
        float4 ab = *(const float4*)(ar + 4);
        float xv[8] = {xa.x, xa.y, xa.z, xa.w, xb.x, xb.y, xb.z, xb.w};
        float av[8] = {aa.x, aa.y, aa.z, aa.w, ab.x, ab.y, ab.z, ab.w};
#pragma unroll
        for (int c = 0; c < 8; c++) {
          float g = fmaxf(xv[c] + av[c], 0.f) + 1e-7f;
          float nm = fmaxf(mM[c], g);
          float sc = __expf(mM[c] - nm);
          float pv = __expf(g - nm);
          sS[c] = sS[c] * sc + pv;
          wW[c] = wW[c] * sc + g * pv;
          mM[c] = nm;
        }
      }
    }
  }

  // merge the 8 per-sub partial states (lanes differing only in bits 3..5)
#pragma unroll
  for (int off = 8; off < 64; off <<= 1) {
#pragma unroll
    for (int c = 0; c < 8; c++) {
      float om = __shfl_xor(mM[c], off, 64);
      float os = __shfl_xor(sS[c], off, 64);
      float ow = __shfl_xor(wW[c], off, 64);
      float M = fmaxf(mM[c], om);
      float e1 = __expf(mM[c] - M), e2 = __expf(om - M);
      sS[c] = sS[c] * e1 + os * e2;
      wW[c] = wW[c] * e1 + ow * e2;
      mM[c] = M;
    }
  }

  if (sub == 0) {
    const float* xr = &x[(size_t)node * DIM + cl * 8];
    float4 xa = *(const float4*)xr;
    float4 xb = *(const float4*)(xr + 4);
    float xv[8] = {xa.x, xa.y, xa.z, xa.w, xb.x, xb.y, xb.z, xb.w};
    float o[8];
#pragma unroll
    for (int c = 0; c < 8; c++) o[c] = wW[c] / fmaxf(sS[c], 1e-16f) + xv[c];
    *(float4*)&h[(size_t)node * DIM + cl * 8] = make_float4(o[0], o[1], o[2], o[3]);
    *(float4*)&h[(size_t)node * DIM + cl * 8 + 4] = make_float4(o[4], o[5], o[6], o[7]);
  }
}

// ---------------- GEMM1: h[N,64] @ W1[64,128] + b1, fused BN partial stats ----------------
// BN partials written TRANSPOSED (ps[ch*tiles + block]) so k_stats can reduce
// with coalesced reads across many blocks (old single-block k_stats was
// latency-bound, ~30us, serialized between gemm1 and gemm2).
__global__ __launch_bounds__(256) void k_gemm1(
    const float* __restrict__ h, const float* __restrict__ W1,
    const float* __restrict__ b1, float* __restrict__ h1,
    float* __restrict__ ps, float* __restrict__ pq, int n) {
  __shared__ float ws[DIM * D2];   // 32 KB
  __shared__ float hs[DIM][68];    // [d][row], padded
  __shared__ float red[8][D2];     // deterministic BN partial reduction
  int tid = threadIdx.x;
  int row0 = blockIdx.x * 64;
  const float4* w4 = (const float4*)W1;
  float4* ws4 = (float4*)ws;
#pragma unroll
  for (int i = 0; i < 8; i++) ws4[tid + 256 * i] = w4[tid + 256 * i];
  const float4* h4 = (const float4*)h;
#pragma unroll
  for (int i = 0; i < 4; i++) {
    int idx = tid + 256 * i;
    int r = idx & 63, dg = idx >> 6;
    int row = row0 + r;
    float4 v = make_float4(0.f, 0.f, 0.f, 0.f);
    if (row < n) v = h4[(size_t)row * 16 + dg];
    int c = dg * 4;
    hs[c + 0][r] = v.x; hs[c + 1][r] = v.y; hs[c + 2][r] = v.z; hs[c + 3][r] = v.w;
  }
  __syncthreads();

  int tc = tid & 31, tr = tid >> 5;  // 4 cols x 8 rows per thread
  float bb[4];
#pragma unroll
  for (int k = 0; k < 4; k++) bb[k] = b1[tc * 4 + k];
  float acc[8][4];
#pragma unroll
  for (int i = 0; i < 8; i++)
#pragma unroll
    for (int k = 0; k < 4; k++) acc[i][k] = bb[k];
  // partial unroll only: full unroll spilled to scratch (R1: 452 MB fetch/dispatch)
#pragma unroll 4
  for (int d = 0; d < DIM; d++) {
    float4 wv = *(const float4*)&ws[d * D2 + tc * 4];
    float4 ha = *(const float4*)&hs[d][tr * 8];
    float4 hb = *(const float4*)&hs[d][tr * 8 + 4];
    float hr[8] = {ha.x, ha.y, ha.z, ha.w, hb.x, hb.y, hb.z, hb.w};
    float wk[4] = {wv.x, wv.y, wv.z, wv.w};
#pragma unroll
    for (int i = 0; i < 8; i++)
#pragma unroll
      for (int k = 0; k < 4; k++) acc[i][k] = fmaf(hr[i], wk[k], acc[i][k]);
  }
  float cs[4] = {0.f, 0.f, 0.f, 0.f}, cq[4] = {0.f, 0.f, 0.f, 0.f};
#pragma unroll
  for (int i = 0; i < 8; i++) {
    int row = row0 + tr * 8 + i;
    if (row < n) {
      ((float4*)h1)[(size_t)row * 32 + tc] =
          make_float4(acc[i][0], acc[i][1], acc[i][2], acc[i][3]);
#pragma unroll
      for (int k = 0; k < 4; k++) { cs[k] += acc[i][k]; cq[k] += acc[i][k] * acc[i][k]; }
    }
  }
  // deterministic (fixed-order) reduction of BN partials — no float atomics
  __syncthreads();
#pragma unroll
  for (int k = 0; k < 4; k++) red[tr][tc * 4 + k] = cs[k];
  __syncthreads();
  float asum = 0.f;
  if (tid < D2) {
#pragma unroll
    for (int r = 0; r < 8; r++) asum += red[r][tid];
  }
  __syncthreads();
#pragma unroll
  for (int k = 0; k < 4; k++) red[tr][tc * 4 + k] = cq[k];
  __syncthreads();
  if (tid < D2) {
    float bsumv = 0.f;
#pragma unroll
    for (int r = 0; r < 8; r++) bsumv += red[r][tid];
    ps[(size_t)tid * gridDim.x + blockIdx.x] = asum;   // transposed
    pq[(size_t)tid * gridDim.x + blockIdx.x] = bsumv;  // transposed
  }
}

// ---------------- finalize BN: fold gamma/beta into scale/shift ----------------
// 128 blocks (one per channel), coalesced reads of transposed partials,
// fixed-order LDS tree -> deterministic.
__global__ __launch_bounds__(256) void k_stats(
    const float* __restrict__ ps, const float* __restrict__ pq,
    const float* __restrict__ gamma, const float* __restrict__ beta,
    float* __restrict__ ss, int rows, int n) {
  __shared__ float r0[256], r1[256];
  int j = blockIdx.x;  // channel
  int t = threadIdx.x;
  float a = 0.f, b = 0.f;
  for (int r = t; r < rows; r += 256) {
    a += ps[(size_t)j * rows + r];
    b += pq[(size_t)j * rows + r];
  }
  r0[t] = a; r1[t] = b;
  __syncthreads();
  for (int off = 128; off > 0; off >>= 1) {
    if (t < off) { r0[t] += r0[t + off]; r1[t] += r1[t + off]; }
    __syncthreads();
  }
  if (t == 0) {
    float mu = r0[0] / (float)n;
    float var = r1[0] / (float)n - mu * mu;
    float sc = gamma[j] * rsqrtf(var + 1e-5f);
    ss[j] = sc;
    ss[D2 + j] = beta[j] - mu * sc;
  }
}

// ---------------- GEMM2: relu(BN(h1))[N,128] @ W2[128,64] + b2 ----------------
__global__ __launch_bounds__(256) void k_gemm2(
    const float* __restrict__ h1, const float* __restrict__ W2,
    const float* __restrict__ b2, const float* __restrict__ ss,
    float* __restrict__ out, int n) {
  __shared__ float ws2[D2 * DIM];  // 32 KB
  __shared__ float hs[D2][68];     // 34.8 KB
  __shared__ float scS[D2], shS[D2];
  int tid = threadIdx.x;
  int row0 = blockIdx.x * 64;
  const float4* w4 = (const float4*)W2;
  float4* ws4 = (float4*)ws2;
#pragma unroll
  for (int i = 0; i < 8; i++) ws4[tid + 256 * i] = w4[tid + 256 * i];
  if (tid < D2) { scS[tid] = ss[tid]; shS[tid] = ss[D2 + tid]; }
  __syncthreads();
  const float4* h14 = (const float4*)h1;
#pragma unroll
  for (int i = 0; i < 8; i++) {
    int idx = tid + 256 * i;
    int r = idx & 63, cg = idx >> 6;
    int row = row0 + r;
    float4 v = make_float4(0.f, 0.f, 0.f, 0.f);
    if (row < n) v = h14[(size_t)row * 32 + cg];
    int c = cg * 4;
    hs[c + 0][r] = fmaxf(fmaf(v.x, scS[c + 0], shS[c + 0]), 0.f);
    hs[c + 1][r] = fmaxf(fmaf(v.y, scS[c + 1], shS[c + 1]), 0.f);
    hs[c + 2][r] = fmaxf(fmaf(v.z, scS[c + 2], shS[c + 2]), 0.f);
    hs[c + 3][r] = fmaxf(fmaf(v.w, scS[c + 3], shS[c + 3]), 0.f);
  }
  __syncthreads();
  int tc = tid & 15, tr = tid >> 4;  // 4 cols x 4 rows per thread
  float bb[4];
#pragma unroll
  for (int k = 0; k < 4; k++) bb[k] = b2[tc * 4 + k];
  float acc[4][4];
#pragma unroll
  for (int i = 0; i < 4; i++)
#pragma unroll
    for (int k = 0; k < 4; k++) acc[i][k] = bb[k];
  // partial unroll only: full unroll spilled to scratch (R1: 452 MB fetch/dispatch)
#pragma unroll 4
  for (int d = 0; d < D2; d++) {
    float4 wv = *(const float4*)&ws2[d * DIM + tc * 4];
    float4 hv = *(const float4*)&hs[d][tr * 4];
    float hr[4] = {hv.x, hv.y, hv.z, hv.w};
    float wk[4] = {wv.x, wv.y, wv.z, wv.w};
#pragma unroll
    for (int i = 0; i < 4; i++)
#pragma unroll
      for (int k = 0; k < 4; k++) acc[i][k] = fmaf(hr[i], wk[k], acc[i][k]);
  }
#pragma unroll
  for (int i = 0; i < 4; i++) {
    int row = row0 + tr * 4 + i;
    if (row < n)
      ((float4*)out)[(size_t)row * 16 + tc] =
          make_float4(acc[i][0], acc[i][1], acc[i][2], acc[i][3]);
  }
}

extern "C" void kernel_launch(void* const* d_in, const int* in_sizes, int n_in,
                              void* d_out, int out_size, void* d_ws, size_t ws_size,
                              hipStream_t stream) {
  (void)n_in; (void)out_size; (void)ws_size;
  const float* x0    = (const float*)d_in[0];
  const int*   ei    = (const int*)d_in[1];
  const float* ea    = (const float*)d_in[2];
  const float* W1    = (const float*)d_in[3];
  const float* b1    = (const float*)d_in[4];
  const float* gamma = (const float*)d_in[5];
  const float* beta  = (const float*)d_in[6];
  const float* W2    = (const float*)d_in[7];
  const float* b2    = (const float*)d_in[8];
  float* out = (float*)d_out;

  int n = in_sizes[0] / DIM;   // 50000
  int m = in_sizes[1] / 2;     // 800000

  char* base = (char*)d_ws;
  size_t off = 0;
  auto alloc = [&](size_t bytes) -> void* {
    void* p = base + off;
    off += (bytes + 255) & ~(size_t)255;
    return p;
  };
  int*   cnt    = (int*)alloc((size_t)n * 4);
  int*   excl   = (int*)alloc((size_t)n * 4);
  int*   bsum   = (int*)alloc(256 * 4);
  int*   boff   = (int*)alloc(256 * 4);
  int*   start  = (int*)alloc((size_t)(n + 1) * 4);
  int*   cursor = (int*)alloc((size_t)n * 4);
  int*   flag   = (int*)alloc(256);
  int2*  sed    = (int2*)alloc((size_t)m * 8);
  float* h      = (float*)alloc((size_t)n * DIM * 4);
  float* h1     = (float*)alloc((size_t)n * D2 * 4);
  int tiles = (n + 63) / 64;
  float* ps = (float*)alloc((size_t)tiles * D2 * 4);
  float* pq = (float*)alloc((size_t)tiles * D2 * 4);
  float* ss = (float*)alloc(256 * 4);

  hipMemsetAsync(cnt, 0, (size_t)n * 4, stream);
  k_detect<<<1, 256, 0, stream>>>(ei, m, flag);
  int mg = (m + 255) / 256;
  int ng = (n + 255) / 256;
  k_hist<<<mg, 256, 0, stream>>>(ei, m, flag, cnt);
  k_scanA<<<ng, 256, 0, stream>>>(cnt, excl, bsum, n);
  k_scanB<<<1, 256, 0, stream>>>(bsum, boff, ng);
  k_scanC<<<ng, 256, 0, stream>>>(excl, boff, start, cursor, n, m);
  k_scatter<<<mg, 256, 0, stream>>>(ei, m, flag, cursor, sed);
  k_sortseg<<<ng, 256, 0, stream>>>(sed, start, n);

  for (int l = 0; l < 3; l++) {
    const float* xin = (l == 0) ? x0 : out;
    k_agg<<<(n + 3) / 4, 256, 0, stream>>>(xin, ea, sed, start, h, n);
    k_gemm1<<<tiles, 256, 0, stream>>>(h, W1 + (size_t)l * DIM * D2, b1 + (size_t)l * D2,
                                       h1, ps, pq, n);
    k_stats<<<D2, 256, 0, stream>>>(ps, pq, gamma + (size_t)l * D2, beta + (size_t)l * D2,
                                    ss, tiles, n);
    k_gemm2<<<tiles, 256, 0, stream>>>(h1, W2 + (size_t)l * D2 * DIM, b2 + (size_t)l * DIM,
                                       ss, out, n);
  }
}